// Round 1
// baseline (1932.724 us; speedup 1.0000x reference)
//
#include <hip/hip_runtime.h>
#include <cstdint>
#include <cstddef>

// Problem constants (fixed by setup_inputs)
#define Bn 16
#define Cn 3
#define Hn 768
#define Wn 768
#define Dn 64
#define HEn 192
#define WEn 192
#define Pn (HEn * WEn)   /* 36864 */
#define HWn (Hn * Wn)    /* 589824 */
#define TOPK 400
#define SENTK 0xFFFFFFFFu

struct Ws {
  float ce_sum[Bn];
  int   ce_cnt[Bn];
  int   cnt1[2][Bn];
  int   cnt2[2][Bn];
  float mu2[2][Bn][Dn];
  float mu1[2][Bn][Dn];
  int   nsel[2][Bn];
  int   idxl[2][Bn][TOPK];
  unsigned keys[2][Bn][Pn];
};
// words to zero: everything before idxl
#define INIT_WORDS (16 + 16 + 32 + 32 + 2048 + 2048 + 32)
static_assert(offsetof(Ws, idxl) == (size_t)INIT_WORDS * 4, "ws layout");
static_assert(sizeof(Ws) < (size_t)6 * 1024 * 1024, "ws small");

__global__ void init_kernel(Ws* ws) {
  unsigned* w = (unsigned*)ws;
  for (int i = threadIdx.x; i < INIT_WORDS; i += blockDim.x) w[i] = 0u;
}

// ---------------- CE loss ----------------
// grid (HWn/4/256, Bn), block 256. 4 pixels/thread via float4.
__global__ void ce_kernel(const float* __restrict__ out, const int* __restrict__ lab,
                          Ws* __restrict__ ws) {
  int b = blockIdx.y;
  int t = blockIdx.x * blockDim.x + threadIdx.x;
  int p4 = t * 4;
  const float* base = out + (size_t)b * Cn * HWn + p4;
  float4 a0 = *(const float4*)(base);
  float4 a1 = *(const float4*)(base + HWn);
  float4 a2 = *(const float4*)(base + 2 * HWn);
  int4 lb = *(const int4*)(lab + (size_t)b * HWn + p4);
  float s = 0.f; int c = 0;
  float x0s[4] = {a0.x, a0.y, a0.z, a0.w};
  float x1s[4] = {a1.x, a1.y, a1.z, a1.w};
  float x2s[4] = {a2.x, a2.y, a2.z, a2.w};
  int ls[4] = {lb.x, lb.y, lb.z, lb.w};
#pragma unroll
  for (int k = 0; k < 4; k++) {
    int l = ls[k];
    if (l != 255) {
      float x0 = x0s[k], x1 = x1s[k], x2 = x2s[k];
      float m = fmaxf(x0, fmaxf(x1, x2));
      float lse = m + __logf(__expf(x0 - m) + __expf(x1 - m) + __expf(x2 - m));
      float xl = (l == 0) ? x0 : ((l == 1) ? x1 : x2);
      s += lse - xl;
      c += 1;
    }
  }
#pragma unroll
  for (int off = 32; off; off >>= 1) {
    s += __shfl_down(s, off);
    c += __shfl_down(c, off);
  }
  if ((threadIdx.x & 63) == 0) {
    atomicAdd(&ws->ce_sum[b], s);
    atomicAdd(&ws->ce_cnt[b], c);
  }
}

// ---------------- main embedding pass ----------------
// grid (Pn/256, Bn, 2), block 256. One downsampled pixel per thread.
__global__ void main_kernel(const float* __restrict__ o0, const float* __restrict__ o1,
                            const float* __restrict__ e0, const float* __restrict__ e1,
                            Ws* __restrict__ ws) {
  int arr = blockIdx.z;
  int b = blockIdx.y;
  int p = blockIdx.x * blockDim.x + threadIdx.x;  // < Pn
  const float* o = (arr ? o1 : o0) + (size_t)b * Cn * HWn;
  int i = p / WEn, j = p - i * WEn;
  int q = (4 * i) * Wn + 4 * j;
  float x0 = o[q], x1 = o[q + HWn], x2 = o[q + 2 * HWn];
  int s = 0; float m = x0;
  if (x1 > m) { m = x1; s = 1; }
  if (x2 > m) { m = x2; s = 2; }
  float conf = 1.0f / (__expf(x0 - m) + __expf(x1 - m) + __expf(x2 - m));
  bool m1 = (s == 1) && (conf > 0.8f);
  bool m2 = (s == 2) && (conf > 0.6f);

  const float* e = (arr ? e1 : e0) + (size_t)b * Dn * Pn + p;
  float v[Dn];
  float sum = 0.f, sq = 0.f;
#pragma unroll
  for (int d = 0; d < Dn; d++) {
    float x = e[(size_t)d * Pn];
    v[d] = x; sum += x; sq += x * x;
  }
  unsigned kb = SENTK;
  if (m1) {
    unsigned u = __float_as_uint(sum);
    kb = (u & 0x80000000u) ? ~u : (u | 0x80000000u);
    if (kb == SENTK) kb--;  // paranoia: finite sums never map here
  }
  ws->keys[arr][b][p] = kb;

  unsigned long long bal1 = __ballot(m1), bal2 = __ballot(m2);
  if ((threadIdx.x & 63) == 0) {
    if (bal1) atomicAdd(&ws->cnt1[arr][b], (int)__popcll(bal1));
    if (bal2) atomicAdd(&ws->cnt2[arr][b], (int)__popcll(bal2));
  }
  if (m2) {
    float rn = rsqrtf(sq);
#pragma unroll
    for (int d = 0; d < Dn; d++) atomicAdd(&ws->mu2[arr][b][d], v[d] * rn);
  }
}

// ---------------- radix select top-400 smallest keys ----------------
// grid 32 (arr*16+b), block 256. MSD radix, 4 bits x 8 levels.
__global__ void select_kernel(Ws* __restrict__ ws) {
  int arr = blockIdx.x >> 4;
  int b = blockIdx.x & 15;
  const unsigned* keys = ws->keys[arr][b];
  int c1 = ws->cnt1[arr][b];
  if (c1 <= TOPK) {
    if (threadIdx.x == 0) ws->nsel[arr][b] = 0;
    return;
  }
  __shared__ int hist[16];
  __shared__ int tieBuf[256];
  __shared__ unsigned sPrefix;
  __shared__ int sKRem, nBelow, nTie;
  if (threadIdx.x == 0) { sPrefix = 0u; sKRem = TOPK; }
  __syncthreads();
  for (int shift = 28; shift >= 0; shift -= 4) {
    if (threadIdx.x < 16) hist[threadIdx.x] = 0;
    __syncthreads();
    unsigned pref = sPrefix;
    for (int p = threadIdx.x; p < Pn; p += blockDim.x) {
      unsigned u = keys[p];
      if (u == SENTK) continue;
      if (shift < 28 && ((u >> (shift + 4)) != (pref >> (shift + 4)))) continue;
      atomicAdd(&hist[(u >> shift) & 15], 1);
    }
    __syncthreads();
    if (threadIdx.x == 0) {
      int k = sKRem, cum = 0, jj = 15;
      for (int t = 0; t < 16; t++) {
        if (cum + hist[t] >= k) { jj = t; k -= cum; break; }
        cum += hist[t];
      }
      sKRem = k;
      sPrefix = pref | ((unsigned)jj << shift);
    }
    __syncthreads();
  }
  unsigned T = sPrefix;
  int kRem = sKRem;
  if (threadIdx.x == 0) { nBelow = 0; nTie = 0; }
  __syncthreads();
  int* idxl = ws->idxl[arr][b];
  for (int p = threadIdx.x; p < Pn; p += blockDim.x) {
    unsigned u = keys[p];
    if (u < T) {
      int pos = atomicAdd(&nBelow, 1);
      if (pos < TOPK) idxl[pos] = p;
    } else if (u == T) {
      int tp = atomicAdd(&nTie, 1);
      if (tp < 256) tieBuf[tp] = p;
    }
  }
  __syncthreads();
  if (threadIdx.x == 0) {
    int nb = nBelow;
    int tn = nTie < 256 ? nTie : 256;
    int take = kRem < tn ? kRem : tn;
    // stable tie-break: smallest pixel indices first (matches stable argsort)
    for (int r = 0; r < take; r++) {
      int mi = r;
      for (int t = r + 1; t < tn; t++)
        if (tieBuf[t] < tieBuf[mi]) mi = t;
      int tmp = tieBuf[r]; tieBuf[r] = tieBuf[mi]; tieBuf[mi] = tmp;
      if (nb + r < TOPK) idxl[nb + r] = tieBuf[r];
    }
    int ns = nb + take;
    ws->nsel[arr][b] = ns > TOPK ? TOPK : ns;
  }
}

// ---------------- class-1 accumulation over selected 400 ----------------
// grid 32, block 256.
__global__ void accum1_kernel(const float* __restrict__ e0, const float* __restrict__ e1,
                              Ws* __restrict__ ws) {
  int arr = blockIdx.x >> 4;
  int b = blockIdx.x & 15;
  int ns = ws->nsel[arr][b];
  const float* e = (arr ? e1 : e0) + (size_t)b * Dn * Pn;
  for (int t = threadIdx.x; t < ns; t += blockDim.x) {
    int p = ws->idxl[arr][b][t];
    float v[Dn];
    float sq = 0.f;
#pragma unroll
    for (int d = 0; d < Dn; d++) {
      float x = e[(size_t)d * Pn + p];
      v[d] = x; sq += x * x;
    }
    float rn = rsqrtf(sq);
#pragma unroll
    for (int d = 0; d < Dn; d++) atomicAdd(&ws->mu1[arr][b][d], v[d] * rn);
  }
}

// ---------------- final combine ----------------
__global__ void final_kernel(Ws* __restrict__ ws, float* __restrict__ out) {
  int t = threadIdx.x;
  float ce = 0.f, num = 0.f;
  int cnt = 0;
  if (t < Bn) {
    int cc = ws->ce_cnt[t];
    ce = ws->ce_sum[t] / (float)(cc > 1 ? cc : 1);
    int c1o = ws->cnt1[0][t], c1a = ws->cnt1[1][t];
    if (c1o > TOPK && c1a > TOPK) {
      float dot = 0.f;
      for (int d = 0; d < Dn; d++) dot += ws->mu1[0][t][d] * ws->mu1[1][t][d];
      num += 1.f - dot / ((float)TOPK * (float)TOPK);
      cnt += 1;
    }
    int c2o = ws->cnt2[0][t], c2a = ws->cnt2[1][t];
    if (c2o > 0 && c2a > 0) {
      float dot = 0.f;
      for (int d = 0; d < Dn; d++) dot += ws->mu2[0][t][d] * ws->mu2[1][t][d];
      float den = (float)(c2o > 1 ? c2o : 1) * (float)(c2a > 1 ? c2a : 1);
      num += 1.f - dot / den;
      cnt += 1;
    }
  }
#pragma unroll
  for (int off = 32; off; off >>= 1) {
    ce += __shfl_down(ce, off);
    num += __shfl_down(num, off);
    cnt += __shfl_down(cnt, off);
  }
  if (t == 0) {
    float loss_ce = ce / (float)Bn;
    float lm = num / (float)(cnt > 1 ? cnt : 1);
    out[0] = loss_ce + 2.f * lm;
    out[1] = loss_ce;
    out[2] = lm;
  }
}

extern "C" void kernel_launch(void* const* d_in, const int* in_sizes, int n_in,
                              void* d_out, int out_size, void* d_ws, size_t ws_size,
                              hipStream_t stream) {
  const float* outputs      = (const float*)d_in[0];
  const float* embeddings   = (const float*)d_in[1];
  const int*   class_labels = (const int*)d_in[2];
  const float* outputs_aug  = (const float*)d_in[3];
  const float* emb_aug      = (const float*)d_in[4];
  // d_in[5] (class_labels_aug) is unused by the reference loss.
  Ws* ws = (Ws*)d_ws;
  float* out = (float*)d_out;

  init_kernel<<<1, 256, 0, stream>>>(ws);
  ce_kernel<<<dim3(HWn / 4 / 256, Bn), 256, 0, stream>>>(outputs, class_labels, ws);
  main_kernel<<<dim3(Pn / 256, Bn, 2), 256, 0, stream>>>(outputs, outputs_aug,
                                                         embeddings, emb_aug, ws);
  select_kernel<<<32, 256, 0, stream>>>(ws);
  accum1_kernel<<<32, 256, 0, stream>>>(embeddings, emb_aug, ws);
  final_kernel<<<1, 64, 0, stream>>>(ws, out);
}

// Round 2
// 788.661 us; speedup vs baseline: 2.4506x; 2.4506x over previous
//
#include <hip/hip_runtime.h>
#include <cstdint>
#include <cstddef>

// Problem constants (fixed by setup_inputs)
#define Bn 16
#define Cn 3
#define Hn 768
#define Wn 768
#define Dn 64
#define HEn 192
#define WEn 192
#define Pn (HEn * WEn)   /* 36864 */
#define HWn (Hn * Wn)    /* 589824 */
#define TOPK 400
#define SENTK 0xFFFFFFFFu
#define PAD 16           /* pad accumulators to one 64B line each */

struct Ws {
  float ce_sum[Bn][PAD];        // 256 words
  int   ce_cnt[Bn][PAD];        // 256
  int   cnt1[2][Bn][PAD];       // 512
  int   cnt2[2][Bn][PAD];       // 512
  float mu2[2][Bn][Dn][PAD];    // 32768
  float mu1[2][Bn][Dn][PAD];    // 32768
  int   nsel[2][Bn];            // 32
  int   idxl[2][Bn][TOPK];      // 12800
  unsigned keys[2][Bn][Pn];     // 1179648
};
#define INIT_WORDS (256 + 256 + 512 + 512 + 32768 + 32768)
static_assert(offsetof(Ws, nsel) == (size_t)INIT_WORDS * 4, "ws layout");
static_assert(sizeof(Ws) < (size_t)6 * 1024 * 1024, "ws small");

__global__ void init_kernel(Ws* ws) {
  unsigned* w = (unsigned*)ws;
  int t = blockIdx.x * blockDim.x + threadIdx.x;
  for (int i = t; i < INIT_WORDS; i += gridDim.x * blockDim.x) w[i] = 0u;
}

__device__ __forceinline__ float wave_sum_f(float s) {
#pragma unroll
  for (int off = 32; off; off >>= 1) s += __shfl_down(s, off);
  return s;
}
__device__ __forceinline__ int wave_sum_i(int s) {
#pragma unroll
  for (int off = 32; off; off >>= 1) s += __shfl_down(s, off);
  return s;
}

// ---------------- CE loss ----------------
// grid (36, Bn), block 256; each thread 16 float4 groups; ONE atomic per block.
__global__ void ce_kernel(const float* __restrict__ out, const int* __restrict__ lab,
                          Ws* __restrict__ ws) {
  int b = blockIdx.y;
  const int NT = 36 * 256;  // threads per image
  int t = blockIdx.x * 256 + threadIdx.x;
  const float* base = out + (size_t)b * Cn * HWn;
  const int* lb_base = lab + (size_t)b * HWn;
  float s = 0.f; int c = 0;
#pragma unroll 4
  for (int it = 0; it < 16; it++) {
    int p4 = (t + it * NT) * 4;
    float4 a0 = *(const float4*)(base + p4);
    float4 a1 = *(const float4*)(base + HWn + p4);
    float4 a2 = *(const float4*)(base + 2 * HWn + p4);
    int4 lb = *(const int4*)(lb_base + p4);
    float x0s[4] = {a0.x, a0.y, a0.z, a0.w};
    float x1s[4] = {a1.x, a1.y, a1.z, a1.w};
    float x2s[4] = {a2.x, a2.y, a2.z, a2.w};
    int ls[4] = {lb.x, lb.y, lb.z, lb.w};
#pragma unroll
    for (int k = 0; k < 4; k++) {
      int l = ls[k];
      if (l != 255) {
        float x0 = x0s[k], x1 = x1s[k], x2 = x2s[k];
        float m = fmaxf(x0, fmaxf(x1, x2));
        float lse = m + __logf(__expf(x0 - m) + __expf(x1 - m) + __expf(x2 - m));
        float xl = (l == 0) ? x0 : ((l == 1) ? x1 : x2);
        s += lse - xl;
        c += 1;
      }
    }
  }
  s = wave_sum_f(s);
  c = wave_sum_i(c);
  __shared__ float ss[4];
  __shared__ int sc[4];
  int wid = threadIdx.x >> 6;
  if ((threadIdx.x & 63) == 0) { ss[wid] = s; sc[wid] = c; }
  __syncthreads();
  if (threadIdx.x == 0) {
    atomicAdd(&ws->ce_sum[b][0], ss[0] + ss[1] + ss[2] + ss[3]);
    atomicAdd(&ws->ce_cnt[b][0], sc[0] + sc[1] + sc[2] + sc[3]);
  }
}

// ---------------- main embedding pass ----------------
// grid (Pn/256, Bn, 2), block 256. One downsampled pixel per thread.
// mu2 accumulated via wave butterfly + LDS -> 64 atomics per BLOCK (padded lines).
__global__ void main_kernel(const float* __restrict__ o0, const float* __restrict__ o1,
                            const float* __restrict__ e0, const float* __restrict__ e1,
                            Ws* __restrict__ ws) {
  int arr = blockIdx.z;
  int b = blockIdx.y;
  int p = blockIdx.x * blockDim.x + threadIdx.x;  // < Pn
  int lane = threadIdx.x & 63, wid = threadIdx.x >> 6;
  const float* o = (arr ? o1 : o0) + (size_t)b * Cn * HWn;
  int i = p / WEn, j = p - i * WEn;
  int q = (4 * i) * Wn + 4 * j;
  float x0 = o[q], x1 = o[q + HWn], x2 = o[q + 2 * HWn];
  int s = 0; float m = x0;
  if (x1 > m) { m = x1; s = 1; }
  if (x2 > m) { m = x2; s = 2; }
  float conf = 1.0f / (__expf(x0 - m) + __expf(x1 - m) + __expf(x2 - m));
  bool m1 = (s == 1) && (conf > 0.8f);
  bool m2 = (s == 2) && (conf > 0.6f);

  const float* e = (arr ? e1 : e0) + (size_t)b * Dn * Pn + p;
  float v[Dn];
  float sum = 0.f, sq = 0.f;
#pragma unroll
  for (int d = 0; d < Dn; d++) {
    float x = e[(size_t)d * Pn];
    v[d] = x; sum += x; sq += x * x;
  }
  unsigned kb = SENTK;
  if (m1) {
    unsigned u = __float_as_uint(sum);
    kb = (u & 0x80000000u) ? ~u : (u | 0x80000000u);
    if (kb == SENTK) kb--;
  }
  ws->keys[arr][b][p] = kb;

  // block-level counts
  __shared__ int scnt1[4], scnt2[4];
  unsigned long long bal1 = __ballot(m1), bal2 = __ballot(m2);
  if (lane == 0) { scnt1[wid] = (int)__popcll(bal1); scnt2[wid] = (int)__popcll(bal2); }

  // mu2 block reduction: butterfly per channel, lane d keeps wave-sum of d
  float rn = m2 ? rsqrtf(sq) : 0.f;
  __shared__ float red[4 * Dn];
  float mine = 0.f;
#pragma unroll
  for (int d = 0; d < Dn; d++) {
    float x = v[d] * rn;
#pragma unroll
    for (int off = 1; off < 64; off <<= 1) x += __shfl_xor(x, off);
    if (lane == d) mine = x;
  }
  red[wid * Dn + lane] = mine;
  __syncthreads();
  if (threadIdx.x < Dn) {
    float S = red[threadIdx.x] + red[Dn + threadIdx.x] +
              red[2 * Dn + threadIdx.x] + red[3 * Dn + threadIdx.x];
    if (S != 0.f) atomicAdd(&ws->mu2[arr][b][threadIdx.x][0], S);
  }
  if (threadIdx.x == 0) {
    int c1 = scnt1[0] + scnt1[1] + scnt1[2] + scnt1[3];
    int c2 = scnt2[0] + scnt2[1] + scnt2[2] + scnt2[3];
    if (c1) atomicAdd(&ws->cnt1[arr][b][0], c1);
    if (c2) atomicAdd(&ws->cnt2[arr][b][0], c2);
  }
}

// ---------------- radix select top-400 smallest keys ----------------
// grid 32 (arr*16+b), block 256. MSD radix, 4 bits x 8 levels.
__global__ void select_kernel(Ws* __restrict__ ws) {
  int arr = blockIdx.x >> 4;
  int b = blockIdx.x & 15;
  const unsigned* keys = ws->keys[arr][b];
  int c1 = ws->cnt1[arr][b][0];
  if (c1 <= TOPK) {
    if (threadIdx.x == 0) ws->nsel[arr][b] = 0;
    return;
  }
  __shared__ int hist[16];
  __shared__ int tieBuf[256];
  __shared__ unsigned sPrefix;
  __shared__ int sKRem, nBelow, nTie;
  if (threadIdx.x == 0) { sPrefix = 0u; sKRem = TOPK; }
  __syncthreads();
  for (int shift = 28; shift >= 0; shift -= 4) {
    if (threadIdx.x < 16) hist[threadIdx.x] = 0;
    __syncthreads();
    unsigned pref = sPrefix;
    for (int p = threadIdx.x; p < Pn; p += blockDim.x) {
      unsigned u = keys[p];
      if (u == SENTK) continue;
      if (shift < 28 && ((u >> (shift + 4)) != (pref >> (shift + 4)))) continue;
      atomicAdd(&hist[(u >> shift) & 15], 1);
    }
    __syncthreads();
    if (threadIdx.x == 0) {
      int k = sKRem, cum = 0, jj = 15;
      for (int t = 0; t < 16; t++) {
        if (cum + hist[t] >= k) { jj = t; k -= cum; break; }
        cum += hist[t];
      }
      sKRem = k;
      sPrefix = pref | ((unsigned)jj << shift);
    }
    __syncthreads();
  }
  unsigned T = sPrefix;
  int kRem = sKRem;
  if (threadIdx.x == 0) { nBelow = 0; nTie = 0; }
  __syncthreads();
  int* idxl = ws->idxl[arr][b];
  for (int p = threadIdx.x; p < Pn; p += blockDim.x) {
    unsigned u = keys[p];
    if (u < T) {
      int pos = atomicAdd(&nBelow, 1);
      if (pos < TOPK) idxl[pos] = p;
    } else if (u == T) {
      int tp = atomicAdd(&nTie, 1);
      if (tp < 256) tieBuf[tp] = p;
    }
  }
  __syncthreads();
  if (threadIdx.x == 0) {
    int nb = nBelow;
    int tn = nTie < 256 ? nTie : 256;
    int take = kRem < tn ? kRem : tn;
    // stable tie-break: smallest pixel indices first (matches stable argsort)
    for (int r = 0; r < take; r++) {
      int mi = r;
      for (int t = r + 1; t < tn; t++)
        if (tieBuf[t] < tieBuf[mi]) mi = t;
      int tmp = tieBuf[r]; tieBuf[r] = tieBuf[mi]; tieBuf[mi] = tmp;
      if (nb + r < TOPK) idxl[nb + r] = tieBuf[r];
    }
    int ns = nb + take;
    ws->nsel[arr][b] = ns > TOPK ? TOPK : ns;
  }
}

// ---------------- class-1 accumulation over selected 400 ----------------
// grid 32, block 256. Per-thread register accumulate + block reduce -> 64 atomics/block.
__global__ void accum1_kernel(const float* __restrict__ e0, const float* __restrict__ e1,
                              Ws* __restrict__ ws) {
  int arr = blockIdx.x >> 4;
  int b = blockIdx.x & 15;
  int ns = ws->nsel[arr][b];
  if (ns == 0) return;  // uniform early exit (before any sync)
  int lane = threadIdx.x & 63, wid = threadIdx.x >> 6;
  const float* e = (arr ? e1 : e0) + (size_t)b * Dn * Pn;
  float acc[Dn];
#pragma unroll
  for (int d = 0; d < Dn; d++) acc[d] = 0.f;
  for (int t = threadIdx.x; t < ns; t += blockDim.x) {
    int p = ws->idxl[arr][b][t];
    float v[Dn];
    float sq = 0.f;
#pragma unroll
    for (int d = 0; d < Dn; d++) {
      float x = e[(size_t)d * Pn + p];
      v[d] = x; sq += x * x;
    }
    float rn = rsqrtf(sq);
#pragma unroll
    for (int d = 0; d < Dn; d++) acc[d] += v[d] * rn;
  }
  __shared__ float red[4 * Dn];
  float mine = 0.f;
#pragma unroll
  for (int d = 0; d < Dn; d++) {
    float x = acc[d];
#pragma unroll
    for (int off = 1; off < 64; off <<= 1) x += __shfl_xor(x, off);
    if (lane == d) mine = x;
  }
  red[wid * Dn + lane] = mine;
  __syncthreads();
  if (threadIdx.x < Dn) {
    float S = red[threadIdx.x] + red[Dn + threadIdx.x] +
              red[2 * Dn + threadIdx.x] + red[3 * Dn + threadIdx.x];
    atomicAdd(&ws->mu1[arr][b][threadIdx.x][0], S);
  }
}

// ---------------- final combine ----------------
__global__ void final_kernel(Ws* __restrict__ ws, float* __restrict__ out) {
  int t = threadIdx.x;
  float ce = 0.f, num = 0.f;
  int cnt = 0;
  if (t < Bn) {
    int cc = ws->ce_cnt[t][0];
    ce = ws->ce_sum[t][0] / (float)(cc > 1 ? cc : 1);
    int c1o = ws->cnt1[0][t][0], c1a = ws->cnt1[1][t][0];
    if (c1o > TOPK && c1a > TOPK) {
      float dot = 0.f;
      for (int d = 0; d < Dn; d++) dot += ws->mu1[0][t][d][0] * ws->mu1[1][t][d][0];
      num += 1.f - dot / ((float)TOPK * (float)TOPK);
      cnt += 1;
    }
    int c2o = ws->cnt2[0][t][0], c2a = ws->cnt2[1][t][0];
    if (c2o > 0 && c2a > 0) {
      float dot = 0.f;
      for (int d = 0; d < Dn; d++) dot += ws->mu2[0][t][d][0] * ws->mu2[1][t][d][0];
      float den = (float)(c2o > 1 ? c2o : 1) * (float)(c2a > 1 ? c2a : 1);
      num += 1.f - dot / den;
      cnt += 1;
    }
  }
#pragma unroll
  for (int off = 32; off; off >>= 1) {
    ce += __shfl_down(ce, off);
    num += __shfl_down(num, off);
    cnt += __shfl_down(cnt, off);
  }
  if (t == 0) {
    float loss_ce = ce / (float)Bn;
    float lm = num / (float)(cnt > 1 ? cnt : 1);
    out[0] = loss_ce + 2.f * lm;
    out[1] = loss_ce;
    out[2] = lm;
  }
}

extern "C" void kernel_launch(void* const* d_in, const int* in_sizes, int n_in,
                              void* d_out, int out_size, void* d_ws, size_t ws_size,
                              hipStream_t stream) {
  const float* outputs      = (const float*)d_in[0];
  const float* embeddings   = (const float*)d_in[1];
  const int*   class_labels = (const int*)d_in[2];
  const float* outputs_aug  = (const float*)d_in[3];
  const float* emb_aug      = (const float*)d_in[4];
  // d_in[5] (class_labels_aug) is unused by the reference loss.
  Ws* ws = (Ws*)d_ws;
  float* out = (float*)d_out;

  init_kernel<<<32, 256, 0, stream>>>(ws);
  ce_kernel<<<dim3(36, Bn), 256, 0, stream>>>(outputs, class_labels, ws);
  main_kernel<<<dim3(Pn / 256, Bn, 2), 256, 0, stream>>>(outputs, outputs_aug,
                                                         embeddings, emb_aug, ws);
  select_kernel<<<32, 256, 0, stream>>>(ws);
  accum1_kernel<<<32, 256, 0, stream>>>(embeddings, emb_aug, ws);
  final_kernel<<<1, 64, 0, stream>>>(ws, out);
}

// Round 3
// 591.309 us; speedup vs baseline: 3.2686x; 1.3338x over previous
//
#include <hip/hip_runtime.h>
#include <cstdint>
#include <cstddef>

// Problem constants (fixed by setup_inputs)
#define Bn 16
#define Cn 3
#define Hn 768
#define Wn 768
#define Dn 64
#define HEn 192
#define WEn 192
#define Pn (HEn * WEn)   /* 36864 */
#define HWn (Hn * Wn)    /* 589824 */
#define TOPK 400
#define SENTK 0xFFFFFFFFu
#define PAD 16           /* pad accumulators to one 64B line each */

struct Ws {
  float ce_sum[Bn][PAD];        // 256 words
  int   ce_cnt[Bn][PAD];        // 256
  int   cnt1[2][Bn][PAD];       // 512
  int   cnt2[2][Bn][PAD];       // 512
  float mu2[2][Bn][Dn][PAD];    // 32768
  float mu1[2][Bn][Dn][PAD];    // 32768
  int   nsel[2][Bn];            // 32
  int   idxl[2][Bn][TOPK];      // 12800
  unsigned keys[2][Bn][Pn];     // 1179648
};
#define INIT_WORDS (256 + 256 + 512 + 512 + 32768 + 32768)
static_assert(offsetof(Ws, nsel) == (size_t)INIT_WORDS * 4, "ws layout");
static_assert(sizeof(Ws) < (size_t)6 * 1024 * 1024, "ws small");

__global__ void init_kernel(Ws* ws) {
  unsigned* w = (unsigned*)ws;
  int t = blockIdx.x * blockDim.x + threadIdx.x;
  for (int i = t; i < INIT_WORDS; i += gridDim.x * blockDim.x) w[i] = 0u;
}

__device__ __forceinline__ float wave_sum_f(float s) {
#pragma unroll
  for (int off = 32; off; off >>= 1) s += __shfl_down(s, off);
  return s;
}
__device__ __forceinline__ int wave_sum_i(int s) {
#pragma unroll
  for (int off = 32; off; off >>= 1) s += __shfl_down(s, off);
  return s;
}

// ---------------- CE loss ----------------
// grid (72, Bn), block 256; each thread 8 float4 groups; ONE atomic per block.
__global__ void ce_kernel(const float* __restrict__ out, const int* __restrict__ lab,
                          Ws* __restrict__ ws) {
  int b = blockIdx.y;
  const int NT = 72 * 256;  // threads per image
  int t = blockIdx.x * 256 + threadIdx.x;
  const float* base = out + (size_t)b * Cn * HWn;
  const int* lb_base = lab + (size_t)b * HWn;
  float s = 0.f; int c = 0;
#pragma unroll
  for (int it = 0; it < 8; it++) {
    int p4 = (t + it * NT) * 4;
    float4 a0 = *(const float4*)(base + p4);
    float4 a1 = *(const float4*)(base + HWn + p4);
    float4 a2 = *(const float4*)(base + 2 * HWn + p4);
    int4 lb = *(const int4*)(lb_base + p4);
    float x0s[4] = {a0.x, a0.y, a0.z, a0.w};
    float x1s[4] = {a1.x, a1.y, a1.z, a1.w};
    float x2s[4] = {a2.x, a2.y, a2.z, a2.w};
    int ls[4] = {lb.x, lb.y, lb.z, lb.w};
#pragma unroll
    for (int k = 0; k < 4; k++) {
      int l = ls[k];
      if (l != 255) {
        float x0 = x0s[k], x1 = x1s[k], x2 = x2s[k];
        float m = fmaxf(x0, fmaxf(x1, x2));
        float lse = m + __logf(__expf(x0 - m) + __expf(x1 - m) + __expf(x2 - m));
        float xl = (l == 0) ? x0 : ((l == 1) ? x1 : x2);
        s += lse - xl;
        c += 1;
      }
    }
  }
  s = wave_sum_f(s);
  c = wave_sum_i(c);
  __shared__ float ss[4];
  __shared__ int sc[4];
  int wid = threadIdx.x >> 6;
  if ((threadIdx.x & 63) == 0) { ss[wid] = s; sc[wid] = c; }
  __syncthreads();
  if (threadIdx.x == 0) {
    atomicAdd(&ws->ce_sum[b][0], ss[0] + ss[1] + ss[2] + ss[3]);
    atomicAdd(&ws->ce_cnt[b][0], sc[0] + sc[1] + sc[2] + sc[3]);
  }
}

// ---------------- main embedding pass ----------------
// grid (Pn/256, Bn, 2), block 256. One downsampled pixel per thread.
__global__ void main_kernel(const float* __restrict__ o0, const float* __restrict__ o1,
                            const float* __restrict__ e0, const float* __restrict__ e1,
                            Ws* __restrict__ ws) {
  int arr = blockIdx.z;
  int b = blockIdx.y;
  int p = blockIdx.x * blockDim.x + threadIdx.x;  // < Pn
  int lane = threadIdx.x & 63, wid = threadIdx.x >> 6;
  const float* o = (arr ? o1 : o0) + (size_t)b * Cn * HWn;
  int i = p / WEn, j = p - i * WEn;
  int q = (4 * i) * Wn + 4 * j;
  float x0 = o[q], x1 = o[q + HWn], x2 = o[q + 2 * HWn];
  int s = 0; float m = x0;
  if (x1 > m) { m = x1; s = 1; }
  if (x2 > m) { m = x2; s = 2; }
  float conf = 1.0f / (__expf(x0 - m) + __expf(x1 - m) + __expf(x2 - m));
  bool m1 = (s == 1) && (conf > 0.8f);
  bool m2 = (s == 2) && (conf > 0.6f);

  const float* e = (arr ? e1 : e0) + (size_t)b * Dn * Pn + p;
  float v[Dn];
  float sum = 0.f, sq = 0.f;
#pragma unroll
  for (int d = 0; d < Dn; d++) {
    float x = e[(size_t)d * Pn];
    v[d] = x; sum += x; sq += x * x;
  }
  unsigned kb = SENTK;
  if (m1) {
    unsigned u = __float_as_uint(sum);
    kb = (u & 0x80000000u) ? ~u : (u | 0x80000000u);
    if (kb == SENTK) kb--;
  }
  ws->keys[arr][b][p] = kb;

  // block-level counts
  __shared__ int scnt1[4], scnt2[4];
  unsigned long long bal1 = __ballot(m1), bal2 = __ballot(m2);
  if (lane == 0) { scnt1[wid] = (int)__popcll(bal1); scnt2[wid] = (int)__popcll(bal2); }

  // mu2 block reduction: butterfly per channel, lane d keeps wave-sum of d
  float rn = m2 ? rsqrtf(sq) : 0.f;
  __shared__ float red[4 * Dn];
  float mine = 0.f;
#pragma unroll
  for (int d = 0; d < Dn; d++) {
    float x = v[d] * rn;
#pragma unroll
    for (int off = 1; off < 64; off <<= 1) x += __shfl_xor(x, off);
    if (lane == d) mine = x;
  }
  red[wid * Dn + lane] = mine;
  __syncthreads();
  if (threadIdx.x < Dn) {
    float S = red[threadIdx.x] + red[Dn + threadIdx.x] +
              red[2 * Dn + threadIdx.x] + red[3 * Dn + threadIdx.x];
    if (S != 0.f) atomicAdd(&ws->mu2[arr][b][threadIdx.x][0], S);
  }
  if (threadIdx.x == 0) {
    int c1 = scnt1[0] + scnt1[1] + scnt1[2] + scnt1[3];
    int c2 = scnt2[0] + scnt2[1] + scnt2[2] + scnt2[3];
    if (c1) atomicAdd(&ws->cnt1[arr][b][0], c1);
    if (c2) atomicAdd(&ws->cnt2[arr][b][0], c2);
  }
}

// ---------------- radix select top-400 smallest keys ----------------
// grid 32 (arr*16+b), block 1024. 11-bit digits x 3 levels (shifts 21/10/0),
// 2048-bin LDS histogram (conflict-free in expectation), 4x batched loads.
__global__ void __launch_bounds__(1024) select_kernel(Ws* __restrict__ ws) {
  int arr = blockIdx.x >> 4;
  int b = blockIdx.x & 15;
  int tid = threadIdx.x;
  const unsigned* __restrict__ keys = ws->keys[arr][b];
  int c1 = ws->cnt1[arr][b][0];
  if (c1 <= TOPK) {
    if (tid == 0) ws->nsel[arr][b] = 0;
    return;
  }
  __shared__ int hist[2048];
  __shared__ int super[128];
  __shared__ int tieBuf[256];
  __shared__ unsigned sPrefix;
  __shared__ int sKRem, nBelow, nTie;
  if (tid == 0) { sPrefix = 0u; sKRem = TOPK; }

  const int shifts[3] = {21, 10, 0};
  const unsigned bmask[3] = {2047u, 2047u, 1023u};
  const int nbins[3] = {2048, 2048, 1024};

  for (int lvl = 0; lvl < 3; lvl++) {
    hist[tid] = 0;
    hist[tid + 1024] = 0;
    __syncthreads();
    unsigned pref = sPrefix;
    int shift = shifts[lvl];
    unsigned bm = bmask[lvl];
    for (int base = tid; base < Pn; base += 4096) {
      unsigned u0 = keys[base];
      unsigned u1 = keys[base + 1024];
      unsigned u2 = keys[base + 2048];
      unsigned u3 = keys[base + 3072];
#pragma unroll
      for (int k = 0; k < 4; k++) {
        unsigned u = (k == 0) ? u0 : (k == 1) ? u1 : (k == 2) ? u2 : u3;
        if (u == SENTK) continue;
        if (lvl == 1 && (u >> 21) != (pref >> 21)) continue;
        if (lvl == 2 && (u >> 10) != (pref >> 10)) continue;
        atomicAdd(&hist[(u >> shift) & bm], 1);
      }
    }
    __syncthreads();
    // parallel reduce to 128 super-bins, then thread0 scans 128+SB entries
    int SB = nbins[lvl] >> 7;  // 16 or 8
    if (tid < 128) {
      int s = 0;
      for (int k = 0; k < SB; k++) s += hist[tid * SB + k];
      super[tid] = s;
    }
    __syncthreads();
    if (tid == 0) {
      int k = sKRem, cum = 0, sb = 127;
      for (int t = 0; t < 128; t++) {
        if (cum + super[t] >= k) { sb = t; break; }
        cum += super[t];
      }
      int j = sb * SB + SB - 1;
      for (int t = sb * SB; t < sb * SB + SB; t++) {
        if (cum + hist[t] >= k) { j = t; k -= cum; break; }
        cum += hist[t];
      }
      sKRem = k;
      sPrefix = pref | ((unsigned)j << shift);
    }
    __syncthreads();
  }
  unsigned T = sPrefix;
  int kRem = sKRem;
  if (tid == 0) { nBelow = 0; nTie = 0; }
  __syncthreads();
  int* idxl = ws->idxl[arr][b];
  for (int base = tid; base < Pn; base += 4096) {
    unsigned u0 = keys[base];
    unsigned u1 = keys[base + 1024];
    unsigned u2 = keys[base + 2048];
    unsigned u3 = keys[base + 3072];
#pragma unroll
    for (int k = 0; k < 4; k++) {
      unsigned u = (k == 0) ? u0 : (k == 1) ? u1 : (k == 2) ? u2 : u3;
      int p = base + k * 1024;
      if (u < T) {
        int pos = atomicAdd(&nBelow, 1);
        if (pos < TOPK) idxl[pos] = p;
      } else if (u == T) {
        int tp = atomicAdd(&nTie, 1);
        if (tp < 256) tieBuf[tp] = p;
      }
    }
  }
  __syncthreads();
  if (tid == 0) {
    int nb = nBelow;
    int tn = nTie < 256 ? nTie : 256;
    int take = kRem < tn ? kRem : tn;
    // stable tie-break: smallest pixel indices first (matches stable argsort)
    for (int r = 0; r < take; r++) {
      int mi = r;
      for (int t = r + 1; t < tn; t++)
        if (tieBuf[t] < tieBuf[mi]) mi = t;
      int tmp = tieBuf[r]; tieBuf[r] = tieBuf[mi]; tieBuf[mi] = tmp;
      if (nb + r < TOPK) idxl[nb + r] = tieBuf[r];
    }
    int ns = nb + take;
    ws->nsel[arr][b] = ns > TOPK ? TOPK : ns;
  }
}

// ---------------- class-1 accumulation over selected 400 ----------------
// grid 32, block 256. Per-thread register accumulate + block reduce -> 64 atomics/block.
__global__ void accum1_kernel(const float* __restrict__ e0, const float* __restrict__ e1,
                              Ws* __restrict__ ws) {
  int arr = blockIdx.x >> 4;
  int b = blockIdx.x & 15;
  int ns = ws->nsel[arr][b];
  if (ns == 0) return;  // uniform early exit (before any sync)
  int lane = threadIdx.x & 63, wid = threadIdx.x >> 6;
  const float* e = (arr ? e1 : e0) + (size_t)b * Dn * Pn;
  float acc[Dn];
#pragma unroll
  for (int d = 0; d < Dn; d++) acc[d] = 0.f;
  for (int t = threadIdx.x; t < ns; t += blockDim.x) {
    int p = ws->idxl[arr][b][t];
    float v[Dn];
    float sq = 0.f;
#pragma unroll
    for (int d = 0; d < Dn; d++) {
      float x = e[(size_t)d * Pn + p];
      v[d] = x; sq += x * x;
    }
    float rn = rsqrtf(sq);
#pragma unroll
    for (int d = 0; d < Dn; d++) acc[d] += v[d] * rn;
  }
  __shared__ float red[4 * Dn];
  float mine = 0.f;
#pragma unroll
  for (int d = 0; d < Dn; d++) {
    float x = acc[d];
#pragma unroll
    for (int off = 1; off < 64; off <<= 1) x += __shfl_xor(x, off);
    if (lane == d) mine = x;
  }
  red[wid * Dn + lane] = mine;
  __syncthreads();
  if (threadIdx.x < Dn) {
    float S = red[threadIdx.x] + red[Dn + threadIdx.x] +
              red[2 * Dn + threadIdx.x] + red[3 * Dn + threadIdx.x];
    atomicAdd(&ws->mu1[arr][b][threadIdx.x][0], S);
  }
}

// ---------------- final combine ----------------
__global__ void final_kernel(Ws* __restrict__ ws, float* __restrict__ out) {
  int t = threadIdx.x;
  float ce = 0.f, num = 0.f;
  int cnt = 0;
  if (t < Bn) {
    int cc = ws->ce_cnt[t][0];
    ce = ws->ce_sum[t][0] / (float)(cc > 1 ? cc : 1);
    int c1o = ws->cnt1[0][t][0], c1a = ws->cnt1[1][t][0];
    if (c1o > TOPK && c1a > TOPK) {
      float dot = 0.f;
      for (int d = 0; d < Dn; d++) dot += ws->mu1[0][t][d][0] * ws->mu1[1][t][d][0];
      num += 1.f - dot / ((float)TOPK * (float)TOPK);
      cnt += 1;
    }
    int c2o = ws->cnt2[0][t][0], c2a = ws->cnt2[1][t][0];
    if (c2o > 0 && c2a > 0) {
      float dot = 0.f;
      for (int d = 0; d < Dn; d++) dot += ws->mu2[0][t][d][0] * ws->mu2[1][t][d][0];
      float den = (float)(c2o > 1 ? c2o : 1) * (float)(c2a > 1 ? c2a : 1);
      num += 1.f - dot / den;
      cnt += 1;
    }
  }
#pragma unroll
  for (int off = 32; off; off >>= 1) {
    ce += __shfl_down(ce, off);
    num += __shfl_down(num, off);
    cnt += __shfl_down(cnt, off);
  }
  if (t == 0) {
    float loss_ce = ce / (float)Bn;
    float lm = num / (float)(cnt > 1 ? cnt : 1);
    out[0] = loss_ce + 2.f * lm;
    out[1] = loss_ce;
    out[2] = lm;
  }
}

extern "C" void kernel_launch(void* const* d_in, const int* in_sizes, int n_in,
                              void* d_out, int out_size, void* d_ws, size_t ws_size,
                              hipStream_t stream) {
  const float* outputs      = (const float*)d_in[0];
  const float* embeddings   = (const float*)d_in[1];
  const int*   class_labels = (const int*)d_in[2];
  const float* outputs_aug  = (const float*)d_in[3];
  const float* emb_aug      = (const float*)d_in[4];
  // d_in[5] (class_labels_aug) is unused by the reference loss.
  Ws* ws = (Ws*)d_ws;
  float* out = (float*)d_out;

  init_kernel<<<32, 256, 0, stream>>>(ws);
  ce_kernel<<<dim3(72, Bn), 256, 0, stream>>>(outputs, class_labels, ws);
  main_kernel<<<dim3(Pn / 256, Bn, 2), 256, 0, stream>>>(outputs, outputs_aug,
                                                         embeddings, emb_aug, ws);
  select_kernel<<<32, 1024, 0, stream>>>(ws);
  accum1_kernel<<<32, 256, 0, stream>>>(embeddings, emb_aug, ws);
  final_kernel<<<1, 64, 0, stream>>>(ws, out);
}

// Round 4
// 530.056 us; speedup vs baseline: 3.6463x; 1.1156x over previous
//
#include <hip/hip_runtime.h>
#include <cstdint>
#include <cstddef>

// Problem constants (fixed by setup_inputs)
#define Bn 16
#define Cn 3
#define Hn 768
#define Wn 768
#define Dn 64
#define HEn 192
#define WEn 192
#define Pn (HEn * WEn)   /* 36864 */
#define HWn (Hn * Wn)    /* 589824 */
#define TOPK 400
#define SENTK 0xFFFFFFFFu
#define PAD 16           /* pad accumulators to one 64B line each */
#define PXB 128          /* pixels per main block */

struct Ws {
  float ce_sum[Bn][PAD];        // 256 words
  int   ce_cnt[Bn][PAD];        // 256
  int   cnt1[2][Bn][PAD];       // 512
  int   cnt2[2][Bn][PAD];       // 512
  float mu2[2][Bn][Dn][PAD];    // 32768
  float mu1[2][Bn][Dn][PAD];    // 32768
  int   nsel[2][Bn];            // 32
  int   idxl[2][Bn][TOPK];      // 12800
  unsigned keys[2][Bn][Pn];     // 1179648
};
#define INIT_WORDS (256 + 256 + 512 + 512 + 32768 + 32768)
static_assert(offsetof(Ws, nsel) == (size_t)INIT_WORDS * 4, "ws layout");
static_assert(sizeof(Ws) < (size_t)6 * 1024 * 1024, "ws small");

__global__ void init_kernel(Ws* ws) {
  unsigned* w = (unsigned*)ws;
  int t = blockIdx.x * blockDim.x + threadIdx.x;
  for (int i = t; i < INIT_WORDS; i += gridDim.x * blockDim.x) w[i] = 0u;
}

__device__ __forceinline__ float wave_sum_f(float s) {
#pragma unroll
  for (int off = 32; off; off >>= 1) s += __shfl_down(s, off);
  return s;
}
__device__ __forceinline__ int wave_sum_i(int s) {
#pragma unroll
  for (int off = 32; off; off >>= 1) s += __shfl_down(s, off);
  return s;
}

// ---------------- CE loss ----------------
// grid (144, Bn), block 256; 4 float4 groups/thread; ONE atomic pair per block.
__global__ void ce_kernel(const float* __restrict__ out, const int* __restrict__ lab,
                          Ws* __restrict__ ws) {
  int b = blockIdx.y;
  const int NT = 144 * 256;  // threads per image
  int t = blockIdx.x * 256 + threadIdx.x;
  const float* base = out + (size_t)b * Cn * HWn;
  const int* lb_base = lab + (size_t)b * HWn;
  float s = 0.f; int c = 0;
#pragma unroll
  for (int it = 0; it < 4; it++) {
    int p4 = (t + it * NT) * 4;
    float4 a0 = *(const float4*)(base + p4);
    float4 a1 = *(const float4*)(base + HWn + p4);
    float4 a2 = *(const float4*)(base + 2 * HWn + p4);
    int4 lb = *(const int4*)(lb_base + p4);
    float x0s[4] = {a0.x, a0.y, a0.z, a0.w};
    float x1s[4] = {a1.x, a1.y, a1.z, a1.w};
    float x2s[4] = {a2.x, a2.y, a2.z, a2.w};
    int ls[4] = {lb.x, lb.y, lb.z, lb.w};
#pragma unroll
    for (int k = 0; k < 4; k++) {
      int l = ls[k];
      if (l != 255) {
        float x0 = x0s[k], x1 = x1s[k], x2 = x2s[k];
        float m = fmaxf(x0, fmaxf(x1, x2));
        float lse = m + __logf(__expf(x0 - m) + __expf(x1 - m) + __expf(x2 - m));
        float xl = (l == 0) ? x0 : ((l == 1) ? x1 : x2);
        s += lse - xl;
        c += 1;
      }
    }
  }
  s = wave_sum_f(s);
  c = wave_sum_i(c);
  __shared__ float ss[4];
  __shared__ int sc[4];
  int wid = threadIdx.x >> 6;
  if ((threadIdx.x & 63) == 0) { ss[wid] = s; sc[wid] = c; }
  __syncthreads();
  if (threadIdx.x == 0) {
    atomicAdd(&ws->ce_sum[b][0], ss[0] + ss[1] + ss[2] + ss[3]);
    atomicAdd(&ws->ce_cnt[b][0], sc[0] + sc[1] + sc[2] + sc[3]);
  }
}

// ---------------- main embedding pass ----------------
// grid (Pn/PXB, Bn, 2), block 256 = 4 waves.
// Layout: 128 pixels/block; wave w owns channels [16w,16w+16); lane owns pixel
// pair (p0+2*lane, +1). Each thread keeps only 32 floats -> no spill (the R3
// kernel's v[64] forced the compiler into reload-from-global; VGPR=40 proved it).
__global__ void main_kernel(const float* __restrict__ o0, const float* __restrict__ o1,
                            const float* __restrict__ e0, const float* __restrict__ e1,
                            Ws* __restrict__ ws) {
  int arr = blockIdx.z;
  int b = blockIdx.y;
  int lane = threadIdx.x & 63, wv = threadIdx.x >> 6;
  int p0 = blockIdx.x * PXB;
  int pa = p0 + 2 * lane;

  const float* e = (arr ? e1 : e0) + ((size_t)b * Dn + wv * 16) * Pn;
  float va[16], vb[16];
  float sum0 = 0.f, sum1 = 0.f, sq0 = 0.f, sq1 = 0.f;
#pragma unroll
  for (int k = 0; k < 16; k++) {
    float2 x = *(const float2*)(e + (size_t)k * Pn + pa);
    va[k] = x.x; vb[k] = x.y;
    sum0 += x.x; sq0 += x.x * x.x;
    sum1 += x.y; sq1 += x.y * x.y;
  }

  __shared__ float psum[4][PXB], psq[4][PXB];
  __shared__ float sscale[PXB];
  *(float2*)&psum[wv][2 * lane] = make_float2(sum0, sum1);
  *(float2*)&psq[wv][2 * lane] = make_float2(sq0, sq1);
  __syncthreads();

  if (wv == 0) {
    const float* o = (arr ? o1 : o0) + (size_t)b * Cn * HWn;
    unsigned kb[2]; float sc[2]; bool m1f[2], m2f[2];
#pragma unroll
    for (int h = 0; h < 2; h++) {
      int px = 2 * lane + h;
      int p = p0 + px;
      float ts = psum[0][px] + psum[1][px] + psum[2][px] + psum[3][px];
      float tq = psq[0][px] + psq[1][px] + psq[2][px] + psq[3][px];
      int i = p / WEn, j = p - i * WEn;
      int q = (4 * i) * Wn + 4 * j;
      float x0 = o[q], x1 = o[q + HWn], x2 = o[q + 2 * HWn];
      int sgc = 0; float m = x0;
      if (x1 > m) { m = x1; sgc = 1; }
      if (x2 > m) { m = x2; sgc = 2; }
      float conf = 1.0f / (__expf(x0 - m) + __expf(x1 - m) + __expf(x2 - m));
      bool m1 = (sgc == 1) && (conf > 0.8f);
      bool m2 = (sgc == 2) && (conf > 0.6f);
      unsigned kbv = SENTK;
      if (m1) {
        unsigned u = __float_as_uint(ts);
        kbv = (u & 0x80000000u) ? ~u : (u | 0x80000000u);
        if (kbv == SENTK) kbv--;
      }
      kb[h] = kbv;
      sc[h] = m2 ? rsqrtf(tq) : 0.f;
      m1f[h] = m1; m2f[h] = m2;
    }
    *(uint2*)&ws->keys[arr][b][pa] = make_uint2(kb[0], kb[1]);
    *(float2*)&sscale[2 * lane] = make_float2(sc[0], sc[1]);
    unsigned long long b10 = __ballot(m1f[0]), b11 = __ballot(m1f[1]);
    unsigned long long b20 = __ballot(m2f[0]), b21 = __ballot(m2f[1]);
    if (lane == 0) {
      int c1 = (int)__popcll(b10) + (int)__popcll(b11);
      int c2 = (int)__popcll(b20) + (int)__popcll(b21);
      if (c1) atomicAdd(&ws->cnt1[arr][b][0], c1);
      if (c2) atomicAdd(&ws->cnt2[arr][b][0], c2);
    }
  }
  __syncthreads();

  float2 s2 = *(const float2*)&sscale[2 * lane];
  float rv = 0.f;
#pragma unroll
  for (int k = 0; k < 16; k++) {
    float x = va[k] * s2.x + vb[k] * s2.y;
#pragma unroll
    for (int off = 1; off < 64; off <<= 1) x += __shfl_xor(x, off);
    if (lane == k) rv = x;
  }
  if (lane < 16 && rv != 0.f)
    atomicAdd(&ws->mu2[arr][b][wv * 16 + lane][0], rv);
}

// ---------------- radix select top-400 smallest keys ----------------
// grid 32 (arr*16+b), block 1024. 11-bit digits x 3 levels (shifts 21/10/0),
// 2048-bin LDS histogram, exact uint4 key loads (9 iters per scan).
__global__ void __launch_bounds__(1024) select_kernel(Ws* __restrict__ ws) {
  int arr = blockIdx.x >> 4;
  int b = blockIdx.x & 15;
  int tid = threadIdx.x;
  const uint4* __restrict__ keys4 = (const uint4*)ws->keys[arr][b];
  int c1 = ws->cnt1[arr][b][0];
  if (c1 <= TOPK) {
    if (tid == 0) ws->nsel[arr][b] = 0;
    return;
  }
  __shared__ int hist[2048];
  __shared__ int super[128];
  __shared__ int tieBuf[256];
  __shared__ unsigned sPrefix;
  __shared__ int sKRem, nBelow, nTie;
  if (tid == 0) { sPrefix = 0u; sKRem = TOPK; }

  const int shifts[3] = {21, 10, 0};
  const unsigned bmask[3] = {2047u, 2047u, 1023u};
  const int nbins[3] = {2048, 2048, 1024};

  for (int lvl = 0; lvl < 3; lvl++) {
    hist[tid] = 0;
    hist[tid + 1024] = 0;
    __syncthreads();
    unsigned pref = sPrefix;
    int shift = shifts[lvl];
    unsigned bm = bmask[lvl];
#pragma unroll
    for (int it = 0; it < 9; it++) {
      uint4 u4 = keys4[it * 1024 + tid];
      unsigned us[4] = {u4.x, u4.y, u4.z, u4.w};
#pragma unroll
      for (int k = 0; k < 4; k++) {
        unsigned u = us[k];
        if (u == SENTK) continue;
        if (lvl == 1 && (u >> 21) != (pref >> 21)) continue;
        if (lvl == 2 && (u >> 10) != (pref >> 10)) continue;
        atomicAdd(&hist[(u >> shift) & bm], 1);
      }
    }
    __syncthreads();
    int SB = nbins[lvl] >> 7;  // 16 or 8
    if (tid < 128) {
      int s = 0;
      for (int k = 0; k < SB; k++) s += hist[tid * SB + k];
      super[tid] = s;
    }
    __syncthreads();
    if (tid == 0) {
      int k = sKRem, cum = 0, sb = 127;
      for (int t = 0; t < 128; t++) {
        if (cum + super[t] >= k) { sb = t; break; }
        cum += super[t];
      }
      int j = sb * SB + SB - 1;
      for (int t = sb * SB; t < sb * SB + SB; t++) {
        if (cum + hist[t] >= k) { j = t; k -= cum; break; }
        cum += hist[t];
      }
      sKRem = k;
      sPrefix = pref | ((unsigned)j << shift);
    }
    __syncthreads();
  }
  unsigned T = sPrefix;
  int kRem = sKRem;
  if (tid == 0) { nBelow = 0; nTie = 0; }
  __syncthreads();
  int* idxl = ws->idxl[arr][b];
#pragma unroll
  for (int it = 0; it < 9; it++) {
    uint4 u4 = keys4[it * 1024 + tid];
    unsigned us[4] = {u4.x, u4.y, u4.z, u4.w};
#pragma unroll
    for (int k = 0; k < 4; k++) {
      unsigned u = us[k];
      int p = (it * 1024 + tid) * 4 + k;
      if (u < T) {
        int pos = atomicAdd(&nBelow, 1);
        if (pos < TOPK) idxl[pos] = p;
      } else if (u == T) {
        int tp = atomicAdd(&nTie, 1);
        if (tp < 256) tieBuf[tp] = p;
      }
    }
  }
  __syncthreads();
  if (tid == 0) {
    int nb = nBelow;
    int tn = nTie < 256 ? nTie : 256;
    int take = kRem < tn ? kRem : tn;
    // stable tie-break: smallest pixel indices first (matches stable argsort)
    for (int r = 0; r < take; r++) {
      int mi = r;
      for (int t = r + 1; t < tn; t++)
        if (tieBuf[t] < tieBuf[mi]) mi = t;
      int tmp = tieBuf[r]; tieBuf[r] = tieBuf[mi]; tieBuf[mi] = tmp;
      if (nb + r < TOPK) idxl[nb + r] = tieBuf[r];
    }
    int ns = nb + take;
    ws->nsel[arr][b] = ns > TOPK ? TOPK : ns;
  }
}

// ---------------- class-1 accumulation over selected 400 ----------------
// grid (7, 32), block 256 = 4 waves x 16 channels, 64 pixels per block chunk.
__global__ void accum1_kernel(const float* __restrict__ e0, const float* __restrict__ e1,
                              Ws* __restrict__ ws) {
  int arr = blockIdx.y >> 4;
  int b = blockIdx.y & 15;
  int chunk = blockIdx.x;
  int ns = ws->nsel[arr][b];
  if (chunk * 64 >= ns) return;  // block-uniform early exit
  int lane = threadIdx.x & 63, wv = threadIdx.x >> 6;
  int t = chunk * 64 + lane;
  bool valid = t < ns;
  int p = valid ? ws->idxl[arr][b][t] : 0;
  const float* e = (arr ? e1 : e0) + ((size_t)b * Dn + wv * 16) * Pn;
  float v[16]; float sq = 0.f;
#pragma unroll
  for (int k = 0; k < 16; k++) {
    float x = e[(size_t)k * Pn + p];
    v[k] = x; sq += x * x;
  }
  __shared__ float psq[4][64];
  psq[wv][lane] = sq;
  __syncthreads();
  float tq = psq[0][lane] + psq[1][lane] + psq[2][lane] + psq[3][lane];
  float s = valid ? rsqrtf(tq) : 0.f;
  float rv = 0.f;
#pragma unroll
  for (int k = 0; k < 16; k++) {
    float x = v[k] * s;
#pragma unroll
    for (int off = 1; off < 64; off <<= 1) x += __shfl_xor(x, off);
    if (lane == k) rv = x;
  }
  if (lane < 16 && rv != 0.f)
    atomicAdd(&ws->mu1[arr][b][wv * 16 + lane][0], rv);
}

// ---------------- final combine ----------------
__global__ void final_kernel(Ws* __restrict__ ws, float* __restrict__ out) {
  int t = threadIdx.x;
  float ce = 0.f, num = 0.f;
  int cnt = 0;
  if (t < Bn) {
    int cc = ws->ce_cnt[t][0];
    ce = ws->ce_sum[t][0] / (float)(cc > 1 ? cc : 1);
    int c1o = ws->cnt1[0][t][0], c1a = ws->cnt1[1][t][0];
    if (c1o > TOPK && c1a > TOPK) {
      float dot = 0.f;
      for (int d = 0; d < Dn; d++) dot += ws->mu1[0][t][d][0] * ws->mu1[1][t][d][0];
      num += 1.f - dot / ((float)TOPK * (float)TOPK);
      cnt += 1;
    }
    int c2o = ws->cnt2[0][t][0], c2a = ws->cnt2[1][t][0];
    if (c2o > 0 && c2a > 0) {
      float dot = 0.f;
      for (int d = 0; d < Dn; d++) dot += ws->mu2[0][t][d][0] * ws->mu2[1][t][d][0];
      float den = (float)(c2o > 1 ? c2o : 1) * (float)(c2a > 1 ? c2a : 1);
      num += 1.f - dot / den;
      cnt += 1;
    }
  }
#pragma unroll
  for (int off = 32; off; off >>= 1) {
    ce += __shfl_down(ce, off);
    num += __shfl_down(num, off);
    cnt += __shfl_down(cnt, off);
  }
  if (t == 0) {
    float loss_ce = ce / (float)Bn;
    float lm = num / (float)(cnt > 1 ? cnt : 1);
    out[0] = loss_ce + 2.f * lm;
    out[1] = loss_ce;
    out[2] = lm;
  }
}

extern "C" void kernel_launch(void* const* d_in, const int* in_sizes, int n_in,
                              void* d_out, int out_size, void* d_ws, size_t ws_size,
                              hipStream_t stream) {
  const float* outputs      = (const float*)d_in[0];
  const float* embeddings   = (const float*)d_in[1];
  const int*   class_labels = (const int*)d_in[2];
  const float* outputs_aug  = (const float*)d_in[3];
  const float* emb_aug      = (const float*)d_in[4];
  // d_in[5] (class_labels_aug) is unused by the reference loss.
  Ws* ws = (Ws*)d_ws;
  float* out = (float*)d_out;

  init_kernel<<<32, 256, 0, stream>>>(ws);
  ce_kernel<<<dim3(144, Bn), 256, 0, stream>>>(outputs, class_labels, ws);
  main_kernel<<<dim3(Pn / PXB, Bn, 2), 256, 0, stream>>>(outputs, outputs_aug,
                                                         embeddings, emb_aug, ws);
  select_kernel<<<32, 1024, 0, stream>>>(ws);
  accum1_kernel<<<dim3(7, 32), 256, 0, stream>>>(embeddings, emb_aug, ws);
  final_kernel<<<1, 64, 0, stream>>>(ws, out);
}